// Round 11
// baseline (20.053 us; speedup 1.0000x reference)
//
#include <hip/hip_runtime.h>
#include <math.h>

#define BM    64
#define RSTR  272                  // u8 row stride in LDS bytes (16B-aligned, 68 dwords)
#define AOFF  0
#define BOFF  (BM * RSTR)          // 17408
#define POFF  (2 * BM * RSTR)      // 34816: partials, 1024 thr x 72 B
#define PSTR  72
#define SOFF  (POFF + 1024 * PSTR) // 108544: row sums [128] f32
#define LDSZ  (SOFF + 128 * 4)     // 109056 B

// v_sad_u8: d = c + sum_k |a.byte[k] - b.byte[k]|  (4 elems + accumulate, 1 instr)
__device__ __forceinline__ unsigned sad8(unsigned a, unsigned b, unsigned c) {
    unsigned d;
    asm("v_sad_u8 %0, %1, %2, %3" : "=v"(d) : "v"(a), "v"(b), "v"(c));
    return d;
}

__global__ __launch_bounds__(1024, 4)
void jaccard_kernel(const float* __restrict__ x1, const float* __restrict__ x2,
                    float* __restrict__ out) {
    extern __shared__ char lds[];
    char*  ATile = lds + AOFF;
    char*  BTile = lds + BOFF;
    char*  Part  = lds + POFF;
    float* sums  = (float*)(lds + SOFF);   // [128]: 0..63 A rows, 64..127 B rows

    const int bi = blockIdx.x, bj = blockIdx.y;
    const int tid = threadIdx.x, lane = tid & 63, wid = tid >> 6;

    // ---- fused staging: 128 rows over 16 waves; sigmoid -> u8 -> pack -> LDS ----
    for (int r = wid; r < 2 * BM; r += 16) {
        const bool  isA = (r < BM);
        const int   row = isA ? r : (r - BM);
        const float* src = isA ? (x1 + (size_t)(bi * BM + row) * 256)
                               : (x2 + (size_t)(bj * BM + row) * 256);
        float4 g = *(const float4*)(src + 4 * lane);
        const float k = 255.0f;
        unsigned q0 = (unsigned)(k / (1.0f + __expf(-g.x)) + 0.5f);
        unsigned q1 = (unsigned)(k / (1.0f + __expf(-g.y)) + 0.5f);
        unsigned q2 = (unsigned)(k / (1.0f + __expf(-g.z)) + 0.5f);
        unsigned q3 = (unsigned)(k / (1.0f + __expf(-g.w)) + 0.5f);

        char* tile = isA ? ATile : BTile;
        *(unsigned*)(tile + row * RSTR + lane * 4) =
            q0 | (q1 << 8) | (q2 << 16) | (q3 << 24);

        int sum = (int)(q0 + q1 + q2 + q3);
        #pragma unroll
        for (int s = 32; s >= 1; s >>= 1)
            sum += __shfl_xor(sum, s, 64);
        if (lane == 0) sums[r] = (float)sum;     // <= 65280: f32-exact
    }
    __syncthreads();

    // ---- main: 4x4 microtile, D quarters, SAD inner loop (identical to R10) ----
    const int s  = tid & 255;
    const int q  = tid >> 8;       // D-quarter: bytes [64q, 64q+64)
    const int tx = s & 15;         // cols {tx + 16n}
    const int ty = s >> 4;         // rows {ty + 16m}

    const char* ab = ATile + ty * RSTR + q * 64;
    const char* bb = BTile + tx * RSTR + q * 64;

    unsigned acc[4][4] = {};       // SAD accumulators (u32)
    #pragma unroll
    for (int cc = 0; cc < 4; ++cc) {               // 4 x 16B chunks per quarter
        uint4 av[4], bv[4];
        #pragma unroll
        for (int m = 0; m < 4; ++m)
            av[m] = *(const uint4*)(ab + m * (16 * RSTR) + cc * 16);
        #pragma unroll
        for (int n = 0; n < 4; ++n)
            bv[n] = *(const uint4*)(bb + n * (16 * RSTR) + cc * 16);
        #pragma unroll
        for (int m = 0; m < 4; ++m)
            #pragma unroll
            for (int n = 0; n < 4; ++n) {
                unsigned a = acc[m][n];
                a = sad8(av[m].x, bv[n].x, a);
                a = sad8(av[m].y, bv[n].y, a);
                a = sad8(av[m].z, bv[n].z, a);
                a = sad8(av[m].w, bv[n].w, a);
                acc[m][n] = a;
            }
    }

    char* pw = Part + (size_t)(q * 256 + s) * PSTR;
    #pragma unroll
    for (int m = 0; m < 4; ++m)
        *(uint4*)(pw + m * 16) = make_uint4(acc[m][0], acc[m][1], acc[m][2], acc[m][3]);
    __syncthreads();

    // epilogue: thread (s,q) owns row ty+16q, cols {tx+16n}
    unsigned sd0 = 0, sd1 = 0, sd2 = 0, sd3 = 0;
    #pragma unroll
    for (int qq = 0; qq < 4; ++qq) {
        uint4 p = *(const uint4*)(Part + (size_t)(qq * 256 + s) * PSTR + q * 16);
        sd0 += p.x; sd1 += p.y; sd2 += p.z; sd3 += p.w;
    }

    const float sa  = sums[ty + 16 * q];
    const float sb0 = sums[64 + tx];
    const float sb1 = sums[64 + tx + 16];
    const float sb2 = sums[64 + tx + 32];
    const float sb3 = sums[64 + tx + 48];

    // inter = (sa + sb - sad)/2 ; union = sa + sb - inter ; all f32-exact ints
    const float t0 = sa + sb0, t1 = sa + sb1, t2 = sa + sb2, t3 = sa + sb3;
    const float i0 = 0.5f * (t0 - (float)sd0);
    const float i1 = 0.5f * (t1 - (float)sd1);
    const float i2 = 0.5f * (t2 - (float)sd2);
    const float i3 = 0.5f * (t3 - (float)sd3);
    const float v0 = i0 / (t0 - i0);
    const float v1 = i1 / (t1 - i1);
    const float v2 = i2 / (t2 - i2);
    const float v3 = i3 / (t3 - i3);

    const int i  = bi * 64 + ty + 16 * q;
    const int j0 = bj * 64 + tx;
    float* outT = out + (size_t)1024 * 1024;

    out[(size_t)i * 1024 + j0]      = v0;
    out[(size_t)i * 1024 + j0 + 16] = v1;
    out[(size_t)i * 1024 + j0 + 32] = v2;
    out[(size_t)i * 1024 + j0 + 48] = v3;
    outT[(size_t)j0        * 1024 + i] = v0;
    outT[(size_t)(j0 + 16) * 1024 + i] = v1;
    outT[(size_t)(j0 + 32) * 1024 + i] = v2;
    outT[(size_t)(j0 + 48) * 1024 + i] = v3;
}

extern "C" void kernel_launch(void* const* d_in, const int* in_sizes, int n_in,
                              void* d_out, int out_size, void* d_ws, size_t ws_size,
                              hipStream_t stream) {
    const float* x1 = (const float*)d_in[0];
    const float* x2 = (const float*)d_in[1];
    float* out = (float*)d_out;

    hipFuncSetAttribute((const void*)jaccard_kernel,
                        hipFuncAttributeMaxDynamicSharedMemorySize, LDSZ);

    dim3 grid(16, 16);   // 256 blocks = 1 per CU, 16 waves/CU
    jaccard_kernel<<<grid, 1024, LDSZ, stream>>>(x1, x2, out);
}

// Round 12
// 17.649 us; speedup vs baseline: 1.1362x; 1.1362x over previous
//
#include <hip/hip_runtime.h>
#include <math.h>

#define RSTR  272                   // tile row stride (u8 bytes): 68 dwords, 16B-aligned
#define AOFF  0
#define BOFF  (64 * RSTR)           // 17408
#define POFF  (2 * 64 * RSTR)       // 34816 : partials
#define PSTR  520                   // per-spatial partial stride: 8q x 8m x 4n u16 = 512 + 8 pad
#define LDSZ  (POFF + 128 * PSTR)   // 34816 + 66560 = 101376 B

// v_sad_u8: d = c + sum_k |a.byte[k] - b.byte[k]|
__device__ __forceinline__ unsigned sad8(unsigned a, unsigned b, unsigned c) {
    unsigned d;
    asm("v_sad_u8 %0, %1, %2, %3" : "=v"(d) : "v"(a), "v"(b), "v"(c));
    return d;
}

// ---- prepass: sigmoid -> u8 (x255, round) + integer row sums (f32-exact) ----
__global__ __launch_bounds__(256)
void prepass(const float* __restrict__ x1, const float* __restrict__ x2,
             unsigned* __restrict__ Aq, unsigned* __restrict__ Bq,
             float* __restrict__ rs) {
    const int wid = threadIdx.x >> 6, lane = threadIdx.x & 63;
    const int r = blockIdx.x * 4 + wid;            // 0..2047
    const bool isA = (r < 1024);
    const int row = isA ? r : (r - 1024);
    const float* src = (isA ? x1 : x2) + (size_t)row * 256;

    float4 g = *(const float4*)(src + 4 * lane);
    const float k = 255.0f;
    unsigned q0 = (unsigned)(k / (1.0f + __expf(-g.x)) + 0.5f);
    unsigned q1 = (unsigned)(k / (1.0f + __expf(-g.y)) + 0.5f);
    unsigned q2 = (unsigned)(k / (1.0f + __expf(-g.z)) + 0.5f);
    unsigned q3 = (unsigned)(k / (1.0f + __expf(-g.w)) + 0.5f);

    (isA ? Aq : Bq)[(size_t)row * 64 + lane] = q0 | (q1 << 8) | (q2 << 16) | (q3 << 24);

    int sum = (int)(q0 + q1 + q2 + q3);
    #pragma unroll
    for (int s = 32; s >= 1; s >>= 1)
        sum += __shfl_xor(sum, s, 64);
    if (lane == 0) rs[r] = (float)sum;             // <= 65280: f32-exact
}

// ---- main: 8x4 microtile, split-D-8, SAD inner loop, u16 partial exchange ----
__global__ __launch_bounds__(1024, 4)
void jaccard_main(const uint4* __restrict__ Aq, const uint4* __restrict__ Bq,
                  const float* __restrict__ rs, float* __restrict__ out) {
    extern __shared__ char lds[];
    char* ATile = lds + AOFF;
    char* BTile = lds + BOFF;
    char* Part  = lds + POFF;

    const int bi = blockIdx.x, bj = blockIdx.y;
    const int tid = threadIdx.x;

    // ---- staging: 1 uint4 load + 1 b128 LDS write per thread per tile ----
    {
        const int row = tid >> 4, c16 = tid & 15;          // 64 rows x 16 u4
        uint4 va = Aq[(size_t)(bi * 64 + row) * 16 + c16];
        *(uint4*)(ATile + row * RSTR + c16 * 16) = va;
        uint4 vb = Bq[(size_t)(bj * 64 + row) * 16 + c16];
        *(uint4*)(BTile + row * RSTR + c16 * 16) = vb;
    }
    __syncthreads();

    // spatial s: 128 threads (ty 0..7 rows {ty+8m}, tx 0..15 cols {tx+16n});
    // q = D-eighth: bytes [32q, 32q+32)
    const int s  = tid & 127;
    const int q  = tid >> 7;
    const int tx = s & 15;
    const int ty = s >> 4;

    const char* ab = ATile + ty * RSTR + q * 32;
    const char* bb = BTile + tx * RSTR + q * 32;

    unsigned acc[8][4] = {};
    #pragma unroll
    for (int cc = 0; cc < 2; ++cc) {                       // 2 x 16B chunks per eighth
        uint4 av[8], bv[4];
        #pragma unroll
        for (int m = 0; m < 8; ++m)
            av[m] = *(const uint4*)(ab + m * (8 * RSTR) + cc * 16);
        #pragma unroll
        for (int n = 0; n < 4; ++n)
            bv[n] = *(const uint4*)(bb + n * (16 * RSTR) + cc * 16);
        #pragma unroll
        for (int m = 0; m < 8; ++m)
            #pragma unroll
            for (int n = 0; n < 4; ++n) {
                unsigned a = acc[m][n];
                a = sad8(av[m].x, bv[n].x, a);
                a = sad8(av[m].y, bv[n].y, a);
                a = sad8(av[m].z, bv[n].z, a);
                a = sad8(av[m].w, bv[n].w, a);
                acc[m][n] = a;
            }
    }

    // ---- partials: u16-packed, layout [s][q][m][n4], b64 per m ----
    {
        char* pw = Part + (size_t)s * PSTR + q * 64;
        #pragma unroll
        for (int m = 0; m < 8; ++m) {
            unsigned p0 = acc[m][0] | (acc[m][1] << 16);   // each <= 8160
            unsigned p1 = acc[m][2] | (acc[m][3] << 16);
            *(uint2*)(pw + m * 8) = make_uint2(p0, p1);
        }
    }
    __syncthreads();

    // ---- epilogue: thread owns row (ty+8*mm), cols {tx+16n} ----
    const int s2  = tid & 127;
    const int mm  = tid >> 7;
    const int ty2 = s2 >> 4;
    const int tx2 = s2 & 15;

    unsigned sd0 = 0, sd1 = 0, sd2 = 0, sd3 = 0;
    const char* pr = Part + (size_t)s2 * PSTR + mm * 8;
    #pragma unroll
    for (int qq = 0; qq < 8; ++qq) {
        uint2 p = *(const uint2*)(pr + qq * 64);
        sd0 += p.x & 0xffff; sd1 += p.x >> 16;
        sd2 += p.y & 0xffff; sd3 += p.y >> 16;
    }

    const int i  = bi * 64 + ty2 + 8 * mm;
    const int j0 = bj * 64 + tx2;

    const float sa  = rs[i];
    const float sb0 = rs[1024 + j0];
    const float sb1 = rs[1024 + j0 + 16];
    const float sb2 = rs[1024 + j0 + 32];
    const float sb3 = rs[1024 + j0 + 48];

    const float t0 = sa + sb0, t1 = sa + sb1, t2 = sa + sb2, t3 = sa + sb3;
    const float i0 = 0.5f * (t0 - (float)sd0);
    const float i1 = 0.5f * (t1 - (float)sd1);
    const float i2 = 0.5f * (t2 - (float)sd2);
    const float i3 = 0.5f * (t3 - (float)sd3);
    const float v0 = i0 / (t0 - i0);
    const float v1 = i1 / (t1 - i1);
    const float v2 = i2 / (t2 - i2);
    const float v3 = i3 / (t3 - i3);

    float* outT = out + (size_t)1024 * 1024;
    out[(size_t)i * 1024 + j0]      = v0;
    out[(size_t)i * 1024 + j0 + 16] = v1;
    out[(size_t)i * 1024 + j0 + 32] = v2;
    out[(size_t)i * 1024 + j0 + 48] = v3;
    outT[(size_t)j0        * 1024 + i] = v0;
    outT[(size_t)(j0 + 16) * 1024 + i] = v1;
    outT[(size_t)(j0 + 32) * 1024 + i] = v2;
    outT[(size_t)(j0 + 48) * 1024 + i] = v3;
}

extern "C" void kernel_launch(void* const* d_in, const int* in_sizes, int n_in,
                              void* d_out, int out_size, void* d_ws, size_t ws_size,
                              hipStream_t stream) {
    const float* x1 = (const float*)d_in[0];
    const float* x2 = (const float*)d_in[1];
    float* out = (float*)d_out;

    unsigned* Aq = (unsigned*)d_ws;                 // 256 KB
    unsigned* Bq = Aq + (size_t)1024 * 64;          // 256 KB
    float*    rs = (float*)(Bq + (size_t)1024 * 64);// 8 KB

    hipFuncSetAttribute((const void*)jaccard_main,
                        hipFuncAttributeMaxDynamicSharedMemorySize, LDSZ);

    prepass<<<512, 256, 0, stream>>>(x1, x2, Aq, Bq, rs);
    jaccard_main<<<dim3(16, 16), 1024, LDSZ, stream>>>((const uint4*)Aq, (const uint4*)Bq,
                                                       rs, out);
}